// Round 2
// baseline (6863.580 us; speedup 1.0000x reference)
//
#include <hip/hip_runtime.h>
#include <hip/hip_bf16.h>

typedef unsigned int u32;
typedef unsigned short u16;
typedef __attribute__((ext_vector_type(8))) short bf16x8;   // 8 bf16 = 4 VGPRs
typedef __attribute__((ext_vector_type(4))) float f32x4;

#define DEVI __device__ __forceinline__

constexpr int AG = 8, H = 100, W = 352, HP = 102, WP = 354;
constexpr int HWp = H * W;          // 35200
constexpr int ALOC = 2;             // agents per slice
constexpr int NPIXL = ALOC * HWp;   // 70400 = 550 * 128
constexpr int NB = 2 * WP + 2 * H;  // 908 border pixels per agent

DEVI u16 f2bf(float f) {
  __hip_bfloat16 h = __float2bfloat16(f);
  return *reinterpret_cast<u16*>(&h);
}
DEVI float bf2f(u16 v) { return __uint_as_float(((u32)v) << 16); }

// ---------------------------------------------------------------------------
// feature slice (2 agents) fp32 NCHW -> padded NHWC bf16 (interior only)
// f is pre-offset to agent a0; dst is a 2-agent local buffer.
__global__ void convert_feat(const float* __restrict__ f, u16* __restrict__ dst) {
  int idx = blockIdx.x * 256 + threadIdx.x;  // NPIXL*64 = 4505600 = 17600*256
  int c = idx & 63;
  int np = idx >> 6;
  int a = np / HWp;
  int r1 = np - a * HWp;
  int h = r1 / W;
  int w = r1 - h * W;
  dst[((size_t)(a * HP + h + 1) * WP + (w + 1)) * 64 + c] =
      f2bf(f[((size_t)(a * 64 + c) * H + h) * W + w]);
}

// zero the 1-pixel border of a padded NHWC buffer with C channels, nA agents
template <int C>
__global__ void zero_border(u16* __restrict__ buf, int nA) {
  constexpr int CH = C / 8;
  int idx = blockIdx.x * 256 + threadIdx.x;
  int pix = idx / CH;
  int cc = (idx - pix * CH) * 8;
  if (pix >= nA * NB) return;
  int a = pix / NB;
  int b = pix - a * NB;
  int h, w;
  if (b < WP) { h = 0; w = b; }
  else if (b < 2 * WP) { h = HP - 1; w = b - WP; }
  else {
    int bb = b - 2 * WP;
    int bb2 = (bb < H) ? bb : bb - H;
    h = 1 + bb2;
    w = (bb < H) ? 0 : (WP - 1);
  }
  size_t off = ((size_t)(a * HP + h) * WP + w) * C + cc;
  *reinterpret_cast<uint4*>(buf + off) = make_uint4(0u, 0u, 0u, 0u);
}

// w [O][I][kh][kw] fp32 -> rp[cb][t][kb][r:128][c:32] bf16 (staging order)
__global__ void repack_w(const float* __restrict__ w, u16* __restrict__ rp,
                         int O, int I, int taps) {
  int idx = blockIdx.x * 256 + threadIdx.x;
  int total = O * I * taps;
  if (idx >= total) return;
  int c = idx & 31;
  int r = (idx >> 5) & 127;
  int rest = idx >> 12;            // [cb][t][kb], kb fastest
  int KB = I >> 5;
  int kb = rest % KB;
  int rest2 = rest / KB;
  int t = rest2 % taps;
  int cbi = rest2 / taps;
  int o = cbi * 128 + r;
  int i = kb * 32 + c;
  rp[idx] = f2bf(w[(size_t)(o * I + i) * taps + t]);  // (o*I+i)*taps + (kh*3+kw)
}

// ---------------------------------------------------------------------------
// Implicit-GEMM conv on a 2-agent slice: padded NHWC bf16 in -> NHWC bf16 out
// (+bias, ReLU). BM=128 pixels, BN=128 couts, BK=32. 4 waves, each 64x64 out.
template <int CIN, int COUT, int TAPS>
__global__ __launch_bounds__(256) void conv_k(
    const u16* __restrict__ in, const u16* __restrict__ wrp,
    const float* __restrict__ bias, u16* __restrict__ out,
    int outHp, int outWp, int outPad) {
  constexpr int BM = 128, BN = 128, BK = 32;
  constexpr int KB = CIN / BK;
  constexpr int KSTEPS = TAPS * KB;
  __shared__ u16 Alds[BM * BK];  // 8 KB, XOR-swizzled 16B units
  __shared__ u16 Blds[BN * BK];  // 8 KB

  const int tid = threadIdx.x;
  const int lane = tid & 63;
  const int wid = tid >> 6;
  const int wr = wid >> 1;
  const int wc = wid & 1;
  const int n0 = blockIdx.x * BM;
  const int cb = blockIdx.y;

  // staging: 512 16B chunks per tile, 2 per thread
  int aglob[2], aswz[2], bglob[2], bswz[2];
#pragma unroll
  for (int i = 0; i < 2; ++i) {
    int c = tid + i * 256;
    int p = c >> 2, u = c & 3;
    int np = n0 + p;
    int a = np / HWp;
    int r1 = np - a * HWp;
    int h = r1 / W;
    int w = r1 - h * W;
    aglob[i] = ((a * HP + h + 1) * WP + (w + 1)) * CIN + u * 8;
    aswz[i] = p * (BK * 2) + ((u ^ (p & 3)) << 4);
    bglob[i] = p * BK + u * 8;                       // p doubles as weight row
    bswz[i] = p * (BK * 2) + ((u ^ (p & 3)) << 4);
  }

  const u16* wt = wrp + (size_t)cb * KSTEPS * (BN * BK);

  f32x4 acc[4][4];
#pragma unroll
  for (int m = 0; m < 4; ++m)
#pragma unroll
    for (int n = 0; n < 4; ++n) acc[m][n] = f32x4{0.f, 0.f, 0.f, 0.f};

  // fragment read offsets: lane wants channels [4g..4g+3] and [16+4g..16+4g+3]
  const int g = lane >> 4;
  const int key = lane & 3;                 // == row&3 for all fragment rows
  const int half8 = (g & 1) * 8;
  const int offLo = (((g >> 1) ^ key) << 4) + half8;
  const int offHi = (((2 + (g >> 1)) ^ key) << 4) + half8;
  const int arow = lane & 15;

  auto ldtap = [&](int s, uint4* av, uint4* bv) {
    int t, kb2;
    if (TAPS == 1) { t = 0; kb2 = s; } else { t = s / KB; kb2 = s % KB; }
    int doff = kb2 * BK;
    if (TAPS == 9) doff += ((t / 3 - 1) * WP + (t % 3 - 1)) * CIN;
    const u16* wtile = wt + (size_t)s * (BN * BK);
#pragma unroll
    for (int i = 0; i < 2; ++i) {
      av[i] = *reinterpret_cast<const uint4*>(in + aglob[i] + doff);
      bv[i] = *reinterpret_cast<const uint4*>(wtile + bglob[i]);
    }
  };

  uint4 av[2], bv[2];
  ldtap(0, av, bv);

  for (int s = 0; s < KSTEPS; ++s) {
    __syncthreads();  // previous reads done
#pragma unroll
    for (int i = 0; i < 2; ++i) {
      *reinterpret_cast<uint4*>(reinterpret_cast<char*>(Alds) + aswz[i]) = av[i];
      *reinterpret_cast<uint4*>(reinterpret_cast<char*>(Blds) + bswz[i]) = bv[i];
    }
    __syncthreads();
    if (s + 1 < KSTEPS) ldtap(s + 1, av, bv);  // prefetch under MFMA

    bf16x8 af[4], bfr[4];
#pragma unroll
    for (int m = 0; m < 4; ++m) {
      int rb = (wr * 64 + m * 16 + arow) * (BK * 2);
      uint2 lo = *reinterpret_cast<const uint2*>(reinterpret_cast<const char*>(Alds) + rb + offLo);
      uint2 hi = *reinterpret_cast<const uint2*>(reinterpret_cast<const char*>(Alds) + rb + offHi);
      uint4 q = make_uint4(lo.x, lo.y, hi.x, hi.y);
      af[m] = *reinterpret_cast<bf16x8*>(&q);
    }
#pragma unroll
    for (int n = 0; n < 4; ++n) {
      int rb = (wc * 64 + n * 16 + arow) * (BK * 2);
      uint2 lo = *reinterpret_cast<const uint2*>(reinterpret_cast<const char*>(Blds) + rb + offLo);
      uint2 hi = *reinterpret_cast<const uint2*>(reinterpret_cast<const char*>(Blds) + rb + offHi);
      uint4 q = make_uint4(lo.x, lo.y, hi.x, hi.y);
      bfr[n] = *reinterpret_cast<bf16x8*>(&q);
    }
#pragma unroll
    for (int m = 0; m < 4; ++m)
#pragma unroll
      for (int n = 0; n < 4; ++n)
        acc[m][n] = __builtin_amdgcn_mfma_f32_16x16x32_bf16(af[m], bfr[n], acc[m][n], 0, 0, 0);
  }

  // epilogue: bias + relu + bf16 store
  float bs[4];
#pragma unroll
  for (int n = 0; n < 4; ++n) bs[n] = bias[cb * BN + wc * 64 + n * 16 + arow];

#pragma unroll
  for (int m = 0; m < 4; ++m) {
#pragma unroll
    for (int rg = 0; rg < 4; ++rg) {
      int ploc = wr * 64 + m * 16 + g * 4 + rg;  // D row = (lane>>4)*4 + reg
      int np = n0 + ploc;
      int a = np / HWp;
      int r1 = np - a * HWp;
      int h = r1 / W;
      int w = r1 - h * W;
      size_t ob = ((size_t)(a * outHp + h + outPad) * outWp + (w + outPad)) * COUT;
#pragma unroll
      for (int n = 0; n < 4; ++n) {
        int ch = cb * BN + wc * 64 + n * 16 + arow;  // D col = lane&15
        float v = acc[m][n][rg] + bs[n];
        out[ob + ch] = f2bf(fmaxf(v, 0.f));
      }
    }
  }
}

// ---------------------------------------------------------------------------
// box-mean pooling over y slice [2][100][352][256] bf16 -> desc [2][50][256]
__global__ void pool_k(const u16* __restrict__ y, const int* __restrict__ boxes,
                       float* __restrict__ desc) {
  int blk = blockIdx.x;  // local: a*50 + k, a in 0..1
  const int* bx = boxes + blk * 4;
  int a = blk / 50;
  int l = bx[0], r = bx[1], u = bx[2], d = bx[3];
  int c = threadIdx.x;
  float s = 0.f;
  for (int h = u; h < d; ++h) {
    const u16* row = y + ((size_t)(a * H + h) * W) * 256 + c;
    for (int w2 = l; w2 < r; ++w2) s += bf2f(row[(size_t)w2 * 256]);
  }
  desc[(size_t)blk * 256 + c] = s / (float)((d - u) * (r - l));
}

// ---------------------------------------------------------------------------
extern "C" void kernel_launch(void* const* d_in, const int* in_sizes, int n_in,
                              void* d_out, int out_size, void* d_ws, size_t ws_size,
                              hipStream_t stream) {
  const float* feature = (const float*)d_in[0];
  const int* boxes = (const int*)d_in[1];
  const float* w1a = (const float*)d_in[2];
  const float* b1a = (const float*)d_in[3];
  const float* w1b = (const float*)d_in[4];
  const float* b1b = (const float*)d_in[5];
  const float* w2a = (const float*)d_in[6];
  const float* b2a = (const float*)d_in[7];
  const float* w2b = (const float*)d_in[8];
  const float* b2b = (const float*)d_in[9];
  const float* w3a = (const float*)d_in[10];
  const float* b3a = (const float*)d_in[11];
  const float* w3b = (const float*)d_in[12];
  const float* b3b = (const float*)d_in[13];
  const float* wDa = (const float*)d_in[14];
  const float* bDa = (const float*)d_in[15];
  const float* wDb = (const float*)d_in[16];
  const float* bDb = (const float*)d_in[17];
  const float* wF = (const float*)d_in[18];
  const float* bF = (const float*)d_in[19];

  // ---- workspace arena (slice buffers): total 124,410,880 B (~118.7 MiB)
  char* ws = (char*)d_ws;
  const size_t SZ128 = (size_t)ALOC * HP * WP * 128 * 2;  // 18,487,296 B
  const size_t SZ256 = (size_t)ALOC * HP * WP * 256 * 2;  // 36,974,592 B
  const size_t SZ64  = (size_t)ALOC * HP * WP * 64 * 2;   //  9,243,648 B
  u16* X  = (u16*)(ws);                                   // 128-ch slice A
  u16* Y  = (u16*)(ws + SZ128);                           // 128-ch slice B
  u16* S0 = (u16*)(ws + 2 * SZ128);                       // 256-ch slice A
  u16* S1 = (u16*)(ws + 2 * SZ128 + SZ256);               // 256-ch slice B
  u16* in64 = (u16*)(ws + 2 * SZ128 + 2 * SZ256);         // 64-ch slice
  u16* rp = (u16*)(ws + 2 * SZ128 + 2 * SZ256 + SZ64);    // repacked weights

  // repacked-weight element offsets
  const size_t o1a = 0;
  const size_t o1b = o1a + (size_t)9 * 64 * 128;
  const size_t o2a = o1b + (size_t)9 * 128 * 128;
  const size_t o2b = o2a + (size_t)9 * 128 * 128;
  const size_t o3a = o2b + (size_t)9 * 128 * 128;
  const size_t o3b = o3a + (size_t)9 * 128 * 256;
  const size_t oDa = o3b + (size_t)9 * 256 * 256;
  const size_t oDb = oDa + (size_t)9 * 256 * 256;
  const size_t oF = oDb + (size_t)256 * 256;

  auto rpk = [&](const float* wsrc, size_t off, int O, int I, int taps) {
    int total = O * I * taps;
    repack_w<<<(total + 255) / 256, 256, 0, stream>>>(wsrc, rp + off, O, I, taps);
  };
  rpk(w1a, o1a, 128, 64, 9);
  rpk(w1b, o1b, 128, 128, 9);
  rpk(w2a, o2a, 128, 128, 9);
  rpk(w2b, o2b, 128, 128, 9);
  rpk(w3a, o3a, 256, 128, 9);
  rpk(w3b, o3b, 256, 256, 9);
  rpk(wDa, oDa, 256, 256, 9);
  rpk(wDb, oDb, 256, 256, 1);
  rpk(wF, oF, 256, 256, 1);

  // borders that are never corrupted: zero once per call
  zero_border<64><<<(ALOC * NB * 8 + 255) / 256, 256, 0, stream>>>(in64, ALOC);
  zero_border<128><<<(ALOC * NB * 16 + 255) / 256, 256, 0, stream>>>(X, ALOC);
  zero_border<128><<<(ALOC * NB * 16 + 255) / 256, 256, 0, stream>>>(Y, ALOC);
  zero_border<256><<<(ALOC * NB * 32 + 255) / 256, 256, 0, stream>>>(S1, ALOC);

  for (int a0 = 0; a0 < AG; a0 += ALOC) {
    // S0's padded-layout border bytes were overwritten by previous slice's
    // unpadded convF output -> re-zero each slice
    zero_border<256><<<(ALOC * NB * 32 + 255) / 256, 256, 0, stream>>>(S0, ALOC);

    convert_feat<<<NPIXL * 64 / 256, 256, 0, stream>>>(
        feature + (size_t)a0 * 64 * H * W, in64);

    conv_k<64, 128, 9><<<dim3(NPIXL / 128, 1), 256, 0, stream>>>(in64, rp + o1a, b1a, X, HP, WP, 1);
    conv_k<128, 128, 9><<<dim3(NPIXL / 128, 1), 256, 0, stream>>>(X, rp + o1b, b1b, Y, HP, WP, 1);
    conv_k<128, 128, 9><<<dim3(NPIXL / 128, 1), 256, 0, stream>>>(Y, rp + o2a, b2a, X, HP, WP, 1);
    conv_k<128, 128, 9><<<dim3(NPIXL / 128, 1), 256, 0, stream>>>(X, rp + o2b, b2b, Y, HP, WP, 1);
    conv_k<128, 256, 9><<<dim3(NPIXL / 128, 2), 256, 0, stream>>>(Y, rp + o3a, b3a, S0, HP, WP, 1);
    conv_k<256, 256, 9><<<dim3(NPIXL / 128, 2), 256, 0, stream>>>(S0, rp + o3b, b3b, S1, HP, WP, 1);
    conv_k<256, 256, 9><<<dim3(NPIXL / 128, 2), 256, 0, stream>>>(S1, rp + oDa, bDa, S0, HP, WP, 1);
    conv_k<256, 256, 1><<<dim3(NPIXL / 128, 2), 256, 0, stream>>>(S0, rp + oDb, bDb, S1, HP, WP, 1);
    // convF writes y (unpadded) into S0
    conv_k<256, 256, 1><<<dim3(NPIXL / 128, 2), 256, 0, stream>>>(S1, rp + oF, bF, S0, H, W, 0);

    pool_k<<<ALOC * 50, 256, 0, stream>>>(S0, boxes + (size_t)a0 * 50 * 4,
                                          ((float*)d_out) + (size_t)a0 * 50 * 256);
  }
}

// Round 3
// 2141.047 us; speedup vs baseline: 3.2057x; 3.2057x over previous
//
#include <hip/hip_runtime.h>
#include <hip/hip_bf16.h>

typedef unsigned int u32;
typedef unsigned short u16;
typedef __attribute__((ext_vector_type(8))) short bf16x8;   // 8 bf16 = 4 VGPRs
typedef __attribute__((ext_vector_type(4))) float f32x4;

#define DEVI __device__ __forceinline__

constexpr int AG = 8, H = 100, W = 352, HP = 102, WP = 354;
constexpr int HWp = H * W;          // 35200
constexpr int ALOC = 2;             // agents per slice
constexpr int NPIXL = ALOC * HWp;   // 70400 = 550 * 128
constexpr int NB = 2 * WP + 2 * H;  // 908 border pixels per agent

DEVI u16 f2bf(float f) {
  __hip_bfloat16 h = __float2bfloat16(f);
  return *reinterpret_cast<u16*>(&h);
}
DEVI float bf2f(u16 v) { return __uint_as_float(((u32)v) << 16); }

// interleaved channel order within each 32-block: stored 8v+j <-> logical
// {4v+j (j<4), 16+4v+(j-4) (j>=4)} so one 16B unit = one MFMA k-fragment.
DEVI int chperm(int j) { int v = j >> 3, r = j & 7; return (r < 4) ? 4 * v + r : 16 + 4 * v + (r - 4); }
DEVI int chlog(int c) { return (c & ~31) + chperm(c & 31); }

typedef __attribute__((address_space(1))) const u32 as1c_u32;
typedef __attribute__((address_space(3))) u32 as3_u32;
DEVI void gload16(const u16* g, u16* l) {
  __builtin_amdgcn_global_load_lds((as1c_u32*)(const void*)g, (as3_u32*)(void*)l, 16, 0, 0);
}

// ---------------------------------------------------------------------------
// feature slice (2 agents) fp32 NCHW -> padded NHWC(permuted) bf16 interior
__global__ void convert_feat(const float* __restrict__ f, u16* __restrict__ dst) {
  int idx = blockIdx.x * 256 + threadIdx.x;
  int c = idx & 63;
  int np = idx >> 6;
  int a = np / HWp;
  int r1 = np - a * HWp;
  int h = r1 / W;
  int w = r1 - h * W;
  int lc = (c & 32) + chperm(c & 31);
  dst[((size_t)(a * HP + h + 1) * WP + (w + 1)) * 64 + c] =
      f2bf(f[((size_t)(a * 64 + lc) * H + h) * W + w]);
}

// zero the 1-pixel border of a padded NHWC buffer with C channels, nA agents
template <int C>
__global__ void zero_border(u16* __restrict__ buf, int nA) {
  constexpr int CH = C / 8;
  int idx = blockIdx.x * 256 + threadIdx.x;
  int pix = idx / CH;
  int cc = (idx - pix * CH) * 8;
  if (pix >= nA * NB) return;
  int a = pix / NB;
  int b = pix - a * NB;
  int h, w;
  if (b < WP) { h = 0; w = b; }
  else if (b < 2 * WP) { h = HP - 1; w = b - WP; }
  else {
    int bb = b - 2 * WP;
    int bb2 = (bb < H) ? bb : bb - H;
    h = 1 + bb2;
    w = (bb < H) ? 0 : (WP - 1);
  }
  size_t off = ((size_t)(a * HP + h) * WP + w) * C + cc;
  *reinterpret_cast<uint4*>(buf + off) = make_uint4(0u, 0u, 0u, 0u);
}

// w [O][I][kh][kw] fp32 -> rp[cb][t][kb][r:128][c:32] bf16, perm on I and O
__global__ void repack_w(const float* __restrict__ w, u16* __restrict__ rp,
                         int O, int I, int taps) {
  int idx = blockIdx.x * 256 + threadIdx.x;
  int total = O * I * taps;
  if (idx >= total) return;
  int c = idx & 31;
  int r = (idx >> 5) & 127;
  int rest = idx >> 12;            // [cb][t][kb], kb fastest
  int KB = I >> 5;
  int kb = rest % KB;
  int rest2 = rest / KB;
  int t = rest2 % taps;
  int cbi = rest2 / taps;
  int o = cbi * 128 + (r & ~31) + chperm(r & 31);
  int i = kb * 32 + chperm(c);
  rp[idx] = f2bf(w[(size_t)(o * I + i) * taps + t]);
}

// ---------------------------------------------------------------------------
// Implicit-GEMM conv, m97 structure: global_load_lds(16B) staging with
// pre-swizzled global source, ds_read_b128 fragments, LDS-staged epilogue.
template <int CIN, int COUT, int TAPS>
__global__ __launch_bounds__(256) void conv_k(
    const u16* __restrict__ in, const u16* __restrict__ wrp,
    const float* __restrict__ bias, u16* __restrict__ out,
    int outHp, int outWp, int outPad) {
  constexpr int BM = 128, BN = 128, BK = 32;
  constexpr int KB = CIN / BK;
  constexpr int KSTEPS = TAPS * KB;
  __shared__ u16 smem[16384];  // 32 KB: loop A@0(8KB) B@8KB; epilogue all 32KB
  u16* Alds = smem;
  u16* Blds = smem + 4096;

  const int tid = threadIdx.x;
  const int lane = tid & 63;
  const int wid = tid >> 6;
  const int wr = wid >> 1;
  const int wc = wid & 1;

  // bijective XCD-aware remap (m204) over the linearized grid
  const int nxb = gridDim.x;
  int nwg = nxb * gridDim.y;
  int orig = blockIdx.y * nxb + blockIdx.x;
  int q = nwg >> 3, r8 = nwg & 7;
  int xcd = orig & 7, pos = orig >> 3;
  int lin = (xcd < r8 ? xcd * (q + 1) : r8 * (q + 1) + (xcd - r8) * q) + pos;
  const int wg = lin % nxb;
  const int cb = lin / nxb;
  const int n0 = wg * BM;

  // staging: per wave 2 A-chunks + 2 B-chunks of 16 rows (1KB) each.
  // LDS dest is linear (lane*16B); global src unit pre-swizzled: u = (lane&3)^((p>>1)&3)
  int aoff[2], boff[2];
  u16 *ldsA[2], *ldsB[2];
#pragma unroll
  for (int i = 0; i < 2; ++i) {
    int p = wid * 32 + i * 16 + (lane >> 2);
    int u = (lane & 3) ^ ((p >> 1) & 3);
    int np2 = n0 + p;
    int a = np2 / HWp;
    int r1 = np2 - a * HWp;
    int h = r1 / W;
    int w = r1 - h * W;
    aoff[i] = ((a * HP + h + 1) * WP + (w + 1)) * CIN + u * 8;
    boff[i] = p * BK + u * 8;
    ldsA[i] = Alds + (wid * 32 + i * 16) * BK;
    ldsB[i] = Blds + (wid * 32 + i * 16) * BK;
  }
  const u16* wt = wrp + (size_t)cb * KSTEPS * (BN * BK);

  f32x4 acc[4][4];
#pragma unroll
  for (int m = 0; m < 4; ++m)
#pragma unroll
    for (int n = 0; n < 4; ++n) acc[m][n] = f32x4{0.f, 0.f, 0.f, 0.f};

  // fragment read offsets: stored unit = g ^ ((arow>>1)&3)  (conflict-free b128)
  const int g = lane >> 4;
  const int arow = lane & 15;
  const int fk = (arow >> 1) & 3;
  int aF[4], bF[4];
#pragma unroll
  for (int m = 0; m < 4; ++m) aF[m] = (wr * 64 + m * 16 + arow) * BK + ((g ^ fk) << 3);
#pragma unroll
  for (int n = 0; n < 4; ++n) bF[n] = (wc * 64 + n * 16 + arow) * BK + ((g ^ fk) << 3);

  for (int s = 0; s < KSTEPS; ++s) {
    __syncthreads();  // prior step's fragment reads done
    int t = (TAPS == 1) ? 0 : s / KB;
    int kb = (TAPS == 1) ? s : s - t * KB;
    int doff = kb * BK + ((TAPS == 9) ? ((t / 3 - 1) * WP + (t % 3 - 1)) * CIN : 0);
    const u16* wtile = wt + (size_t)s * (BN * BK);
#pragma unroll
    for (int i = 0; i < 2; ++i) {
      gload16(in + aoff[i] + doff, ldsA[i]);
      gload16(wtile + boff[i], ldsB[i]);
    }
    __syncthreads();  // compiler drains vmcnt before barrier -> tile ready

    bf16x8 af[4], bfr[4];
#pragma unroll
    for (int m = 0; m < 4; ++m) af[m] = *reinterpret_cast<const bf16x8*>(Alds + aF[m]);
#pragma unroll
    for (int n = 0; n < 4; ++n) bfr[n] = *reinterpret_cast<const bf16x8*>(Blds + bF[n]);
#pragma unroll
    for (int m = 0; m < 4; ++m)
#pragma unroll
      for (int n = 0; n < 4; ++n)
        acc[m][n] = __builtin_amdgcn_mfma_f32_16x16x32_bf16(af[m], bfr[n], acc[m][n], 0, 0, 0);
  }

  // ---- epilogue: bias+relu -> per-wave 8KB LDS tile (XOR-swizzled) -> uint4 stores
  __syncthreads();
  float bs[4];
#pragma unroll
  for (int n = 0; n < 4; ++n) {
    int cs = cb * BN + wc * 64 + n * 16 + arow;
    bs[n] = bias[chlog(cs)];
  }
  u16* et = smem + wid * 4096;  // 64 pix x 64 ch
#pragma unroll
  for (int m = 0; m < 4; ++m)
#pragma unroll
    for (int rg = 0; rg < 4; ++rg) {
      int row = m * 16 + g * 4 + rg;
#pragma unroll
      for (int n = 0; n < 4; ++n) {
        int col = (n * 16 + arow) ^ (g << 4);  // bank-spread the 4 g-groups
        float v = acc[m][n][rg] + bs[n];
        et[row * 64 + col] = f2bf(fmaxf(v, 0.f));
      }
    }
  __syncthreads();
#pragma unroll
  for (int j = 0; j < 8; ++j) {
    int p = j * 8 + (lane >> 3);
    int un = lane & 7;
    int su = un ^ (((p >> 2) & 3) << 1);
    uint4 qv = *reinterpret_cast<const uint4*>(et + p * 64 + su * 8);
    int np2 = n0 + wr * 64 + p;
    int a = np2 / HWp;
    int r1 = np2 - a * HWp;
    int h = r1 / W;
    int w = r1 - h * W;
    size_t ob = ((size_t)(a * outHp + h + outPad) * outWp + (w + outPad)) * COUT +
                cb * BN + wc * 64 + un * 8;
    *reinterpret_cast<uint4*>(out + ob) = qv;
  }
}

// ---------------------------------------------------------------------------
// box-mean pooling over y slice [2][100][352][256] bf16(permuted) -> desc fp32
__global__ void pool_k(const u16* __restrict__ y, const int* __restrict__ boxes,
                       float* __restrict__ desc) {
  int blk = blockIdx.x;  // local: a*50 + k, a in 0..1
  const int* bx = boxes + blk * 4;
  int a = blk / 50;
  int l = bx[0], r = bx[1], u = bx[2], d = bx[3];
  int c = threadIdx.x;
  float s = 0.f;
  for (int h = u; h < d; ++h) {
    const u16* row = y + ((size_t)(a * H + h) * W) * 256 + c;
    for (int w2 = l; w2 < r; ++w2) s += bf2f(row[(size_t)w2 * 256]);
  }
  desc[(size_t)blk * 256 + chlog(c)] = s / (float)((d - u) * (r - l));
}

// ---------------------------------------------------------------------------
extern "C" void kernel_launch(void* const* d_in, const int* in_sizes, int n_in,
                              void* d_out, int out_size, void* d_ws, size_t ws_size,
                              hipStream_t stream) {
  const float* feature = (const float*)d_in[0];
  const int* boxes = (const int*)d_in[1];
  const float* w1a = (const float*)d_in[2];
  const float* b1a = (const float*)d_in[3];
  const float* w1b = (const float*)d_in[4];
  const float* b1b = (const float*)d_in[5];
  const float* w2a = (const float*)d_in[6];
  const float* b2a = (const float*)d_in[7];
  const float* w2b = (const float*)d_in[8];
  const float* b2b = (const float*)d_in[9];
  const float* w3a = (const float*)d_in[10];
  const float* b3a = (const float*)d_in[11];
  const float* w3b = (const float*)d_in[12];
  const float* b3b = (const float*)d_in[13];
  const float* wDa = (const float*)d_in[14];
  const float* bDa = (const float*)d_in[15];
  const float* wDb = (const float*)d_in[16];
  const float* bDb = (const float*)d_in[17];
  const float* wF = (const float*)d_in[18];
  const float* bF = (const float*)d_in[19];

  // ---- workspace arena (slice buffers): total ~118.7 MiB
  char* ws = (char*)d_ws;
  const size_t SZ128 = (size_t)ALOC * HP * WP * 128 * 2;  // 18,487,296 B
  const size_t SZ256 = (size_t)ALOC * HP * WP * 256 * 2;  // 36,974,592 B
  const size_t SZ64  = (size_t)ALOC * HP * WP * 64 * 2;   //  9,243,648 B
  u16* X  = (u16*)(ws);
  u16* Y  = (u16*)(ws + SZ128);
  u16* S0 = (u16*)(ws + 2 * SZ128);
  u16* S1 = (u16*)(ws + 2 * SZ128 + SZ256);
  u16* in64 = (u16*)(ws + 2 * SZ128 + 2 * SZ256);
  u16* rp = (u16*)(ws + 2 * SZ128 + 2 * SZ256 + SZ64);

  const size_t o1a = 0;
  const size_t o1b = o1a + (size_t)9 * 64 * 128;
  const size_t o2a = o1b + (size_t)9 * 128 * 128;
  const size_t o2b = o2a + (size_t)9 * 128 * 128;
  const size_t o3a = o2b + (size_t)9 * 128 * 128;
  const size_t o3b = o3a + (size_t)9 * 128 * 256;
  const size_t oDa = o3b + (size_t)9 * 256 * 256;
  const size_t oDb = oDa + (size_t)9 * 256 * 256;
  const size_t oF = oDb + (size_t)256 * 256;

  auto rpk = [&](const float* wsrc, size_t off, int O, int I, int taps) {
    int total = O * I * taps;
    repack_w<<<(total + 255) / 256, 256, 0, stream>>>(wsrc, rp + off, O, I, taps);
  };
  rpk(w1a, o1a, 128, 64, 9);
  rpk(w1b, o1b, 128, 128, 9);
  rpk(w2a, o2a, 128, 128, 9);
  rpk(w2b, o2b, 128, 128, 9);
  rpk(w3a, o3a, 256, 128, 9);
  rpk(w3b, o3b, 256, 256, 9);
  rpk(wDa, oDa, 256, 256, 9);
  rpk(wDb, oDb, 256, 256, 1);
  rpk(wF, oF, 256, 256, 1);

  // borders never corrupted: zero once per call
  zero_border<64><<<(ALOC * NB * 8 + 255) / 256, 256, 0, stream>>>(in64, ALOC);
  zero_border<128><<<(ALOC * NB * 16 + 255) / 256, 256, 0, stream>>>(X, ALOC);
  zero_border<128><<<(ALOC * NB * 16 + 255) / 256, 256, 0, stream>>>(Y, ALOC);
  zero_border<256><<<(ALOC * NB * 32 + 255) / 256, 256, 0, stream>>>(S1, ALOC);

  for (int a0 = 0; a0 < AG; a0 += ALOC) {
    // S0's padded border was overwritten by previous slice's unpadded convF
    zero_border<256><<<(ALOC * NB * 32 + 255) / 256, 256, 0, stream>>>(S0, ALOC);

    convert_feat<<<NPIXL * 64 / 256, 256, 0, stream>>>(
        feature + (size_t)a0 * 64 * H * W, in64);

    conv_k<64, 128, 9><<<dim3(NPIXL / 128, 1), 256, 0, stream>>>(in64, rp + o1a, b1a, X, HP, WP, 1);
    conv_k<128, 128, 9><<<dim3(NPIXL / 128, 1), 256, 0, stream>>>(X, rp + o1b, b1b, Y, HP, WP, 1);
    conv_k<128, 128, 9><<<dim3(NPIXL / 128, 1), 256, 0, stream>>>(Y, rp + o2a, b2a, X, HP, WP, 1);
    conv_k<128, 128, 9><<<dim3(NPIXL / 128, 1), 256, 0, stream>>>(X, rp + o2b, b2b, Y, HP, WP, 1);
    conv_k<128, 256, 9><<<dim3(NPIXL / 128, 2), 256, 0, stream>>>(Y, rp + o3a, b3a, S0, HP, WP, 1);
    conv_k<256, 256, 9><<<dim3(NPIXL / 128, 2), 256, 0, stream>>>(S0, rp + o3b, b3b, S1, HP, WP, 1);
    conv_k<256, 256, 9><<<dim3(NPIXL / 128, 2), 256, 0, stream>>>(S1, rp + oDa, bDa, S0, HP, WP, 1);
    conv_k<256, 256, 1><<<dim3(NPIXL / 128, 2), 256, 0, stream>>>(S0, rp + oDb, bDb, S1, HP, WP, 1);
    conv_k<256, 256, 1><<<dim3(NPIXL / 128, 2), 256, 0, stream>>>(S1, rp + oF, bF, S0, H, W, 0);

    pool_k<<<ALOC * 50, 256, 0, stream>>>(S0, boxes + (size_t)a0 * 50 * 4,
                                          ((float*)d_out) + (size_t)a0 * 50 * 256);
  }
}

// Round 4
// 2113.336 us; speedup vs baseline: 3.2477x; 1.0131x over previous
//
#include <hip/hip_runtime.h>
#include <hip/hip_bf16.h>

typedef unsigned int u32;
typedef unsigned short u16;
typedef __attribute__((ext_vector_type(8))) short bf16x8;   // 8 bf16 = 4 VGPRs
typedef __attribute__((ext_vector_type(4))) float f32x4;

#define DEVI __device__ __forceinline__

constexpr int AG = 8, H = 100, W = 352, HP = 102, WP = 354;
constexpr int HWp = H * W;          // 35200
constexpr int ALOC = 2;             // agents per slice
constexpr int NPIXL = ALOC * HWp;   // 70400 = 550 * 128
constexpr int NB = 2 * WP + 2 * H;  // 908 border pixels per agent

DEVI u16 f2bf(float f) {
  __hip_bfloat16 h = __float2bfloat16(f);
  return *reinterpret_cast<u16*>(&h);
}
DEVI float bf2f(u16 v) { return __uint_as_float(((u32)v) << 16); }

// interleaved channel order within each 32-block: stored 8v+j <-> logical
// {4v+j (j<4), 16+4v+(j-4) (j>=4)} so one 16B unit = one MFMA k-fragment.
DEVI int chperm(int j) { int v = j >> 3, r = j & 7; return (r < 4) ? 4 * v + r : 16 + 4 * v + (r - 4); }
DEVI int chlog(int c) { return (c & ~31) + chperm(c & 31); }

typedef __attribute__((address_space(1))) const u32 as1c_u32;
typedef __attribute__((address_space(3))) u32 as3_u32;
DEVI void gload16(const u16* g, u16* l) {
  __builtin_amdgcn_global_load_lds((as1c_u32*)(const void*)g, (as3_u32*)(void*)l, 16, 0, 0);
}

// ---------------------------------------------------------------------------
// feature slice (2 agents) fp32 NCHW -> padded NHWC(permuted) bf16 interior
__global__ void convert_feat(const float* __restrict__ f, u16* __restrict__ dst) {
  int idx = blockIdx.x * 256 + threadIdx.x;
  int c = idx & 63;
  int np = idx >> 6;
  int a = np / HWp;
  int r1 = np - a * HWp;
  int h = r1 / W;
  int w = r1 - h * W;
  int lc = (c & 32) + chperm(c & 31);
  dst[((size_t)(a * HP + h + 1) * WP + (w + 1)) * 64 + c] =
      f2bf(f[((size_t)(a * 64 + lc) * H + h) * W + w]);
}

// zero the 1-pixel border of a padded NHWC buffer with C channels, nA agents
template <int C>
__global__ void zero_border(u16* __restrict__ buf, int nA) {
  constexpr int CH = C / 8;
  int idx = blockIdx.x * 256 + threadIdx.x;
  int pix = idx / CH;
  int cc = (idx - pix * CH) * 8;
  if (pix >= nA * NB) return;
  int a = pix / NB;
  int b = pix - a * NB;
  int h, w;
  if (b < WP) { h = 0; w = b; }
  else if (b < 2 * WP) { h = HP - 1; w = b - WP; }
  else {
    int bb = b - 2 * WP;
    int bb2 = (bb < H) ? bb : bb - H;
    h = 1 + bb2;
    w = (bb < H) ? 0 : (WP - 1);
  }
  size_t off = ((size_t)(a * HP + h) * WP + w) * C + cc;
  *reinterpret_cast<uint4*>(buf + off) = make_uint4(0u, 0u, 0u, 0u);
}

// w [O][I][kh][kw] fp32 -> rp[s=t*KB+kb][r:O][u:8][jj:8] bf16 with the LDS
// row-XOR swizzle baked in: stored (r,u) holds logical unit lu = u^(r&7).
__global__ void repack_w(const float* __restrict__ w, u16* __restrict__ rp,
                         int O, int I, int taps) {
  int idx = blockIdx.x * 256 + threadIdx.x;
  int total = O * I * taps;
  if (idx >= total) return;
  int jj = idx & 7;
  int u = (idx >> 3) & 7;
  int r = (idx >> 6) % O;
  int s = idx / (O * 64);
  int KB = I >> 6;
  int kb = s % KB;
  int t = s / KB;
  int lu = u ^ (r & 7);
  int g = lu & 3, j32 = lu >> 2;
  int cp = (jj < 4) ? 4 * g + jj : 16 + 4 * g + (jj - 4);
  int i = kb * 64 + j32 * 32 + cp;
  int o = (r & ~31) + chperm(r & 31);
  rp[idx] = f2bf(w[((size_t)o * I + i) * taps + t]);
}

// ---------------------------------------------------------------------------
// Implicit-GEMM conv, BK=64, single block-column (BN=COUT).
// BM=128 pixels. BN=128 -> 256 thr (2x2 waves); BN=256 -> 512 thr (2x4 waves).
// A LDS: [128 rows][8 units] XOR-swizzled via pre-swizzled global source;
// B LDS: linear copy of pre-swizzled repacked weights.
template <int CIN, int BN, int TAPS>
__global__ __launch_bounds__(BN * 2, BN == 256 ? 4 : 3) void conv_k(
    const u16* __restrict__ in, const u16* __restrict__ wrp,
    const float* __restrict__ bias, u16* __restrict__ out,
    int outHp, int outWp, int outPad) {
  constexpr int BM = 128, BK = 64;
  constexpr int KB = CIN / BK;         // 1,2,4
  constexpr int KSTEPS = TAPS * KB;
  constexpr int NT = BN * 2;           // threads
  constexpr int WN = BN / 64;          // waves along N
  constexpr int ACH = 1024 / NT;       // A chunks/thread (4 or 2)
  constexpr int BCH = BN * 8 / NT;     // B chunks/thread (4)
  __shared__ u16 smem[(BM + BN) * BK]; // 32 KB or 48 KB
  u16* Alds = smem;
  u16* Blds = smem + BM * BK;

  const int tid = threadIdx.x;
  const int lane = tid & 63;
  const int wid = tid >> 6;
  const int wr = wid / WN;             // 0..1
  const int wc = wid % WN;

  // bijective XCD-aware remap (m204)
  int nwg = gridDim.x;
  int orig = blockIdx.x;
  int q = nwg >> 3, r8 = nwg & 7;
  int xcd = orig & 7, pos = orig >> 3;
  int wg = (xcd < r8 ? xcd * (q + 1) : r8 * (q + 1) + (xcd - r8) * q) + pos;
  const int n0 = wg * BM;

  // A staging addresses: chunk c = p*8+u; global supplies lu = u^(p&7)
  int aoff[ACH];
#pragma unroll
  for (int i = 0; i < ACH; ++i) {
    int c = tid + i * NT;
    int p = c >> 3, u = c & 7;
    int lu = u ^ (p & 7);
    int np2 = n0 + p;
    int a = np2 / HWp;
    int r1 = np2 - a * HWp;
    int h = r1 / W;
    int w = r1 - h * W;
    aoff[i] = ((a * HP + h + 1) * WP + (w + 1)) * CIN + lu * 8;
  }

  f32x4 acc[4][4];
#pragma unroll
  for (int m = 0; m < 4; ++m)
#pragma unroll
    for (int n = 0; n < 4; ++n) acc[m][n] = f32x4{0.f, 0.f, 0.f, 0.f};

  const int g = lane >> 4;
  const int arow = lane & 15;
  const int fk = arow & 7;

  for (int s = 0; s < KSTEPS; ++s) {
    __syncthreads();  // prior step's fragment reads done
    int t = (TAPS == 1) ? 0 : s / KB;
    int kb = (TAPS == 1) ? s : s - t * KB;
    int doff = kb * BK + ((TAPS == 9) ? ((t / 3 - 1) * WP + (t % 3 - 1)) * CIN : 0);
    const u16* wtile = wrp + (size_t)s * (BN * BK);
#pragma unroll
    for (int i = 0; i < ACH; ++i)
      gload16(in + aoff[i] + doff, Alds + (tid + i * NT) * 8);
#pragma unroll
    for (int i = 0; i < BCH; ++i)
      gload16(wtile + (tid + i * NT) * 8, Blds + (tid + i * NT) * 8);
    __syncthreads();  // vmcnt drained at barrier -> tile ready

#pragma unroll
    for (int j = 0; j < 2; ++j) {
      bf16x8 af[4], bfr[4];
#pragma unroll
      for (int m = 0; m < 4; ++m)
        af[m] = *reinterpret_cast<const bf16x8*>(
            Alds + (wr * 64 + m * 16 + arow) * 64 + (((j * 4 + g) ^ fk) << 3));
#pragma unroll
      for (int n = 0; n < 4; ++n)
        bfr[n] = *reinterpret_cast<const bf16x8*>(
            Blds + (wc * 64 + n * 16 + arow) * 64 + (((j * 4 + g) ^ fk) << 3));
#pragma unroll
      for (int m = 0; m < 4; ++m)
#pragma unroll
        for (int n = 0; n < 4; ++n)
          acc[m][n] = __builtin_amdgcn_mfma_f32_16x16x32_bf16(af[m], bfr[n], acc[m][n], 0, 0, 0);
    }
  }

  // ---- epilogue: bias+relu -> per-wave 4KB LDS tile (2 passes of 32 px)
  __syncthreads();
  float bs[4];
#pragma unroll
  for (int n = 0; n < 4; ++n) bs[n] = bias[chlog(wc * 64 + n * 16 + arow)];
  u16* et = smem + wid * 2048;  // 32 px x 64 ch per wave
#pragma unroll
  for (int pp = 0; pp < 2; ++pp) {
    if (pp) __syncthreads();
#pragma unroll
    for (int mm = 0; mm < 2; ++mm) {
      int m = pp * 2 + mm;
#pragma unroll
      for (int rg = 0; rg < 4; ++rg) {
        int row = mm * 16 + g * 4 + rg;  // 0..31; (row>>2)&3 == g
#pragma unroll
        for (int n = 0; n < 4; ++n) {
          int col = (n * 16 + arow) ^ (g << 4);
          et[row * 64 + col] = f2bf(fmaxf(acc[m][n][rg] + bs[n], 0.f));
        }
      }
    }
    __syncthreads();
#pragma unroll
    for (int jj = 0; jj < 4; ++jj) {
      int p = jj * 8 + (lane >> 3);  // 0..31
      int un = lane & 7;
      int su = un ^ (((p >> 2) & 3) << 1);
      uint4 qv = *reinterpret_cast<const uint4*>(et + p * 64 + su * 8);
      int np2 = n0 + wr * 64 + pp * 32 + p;
      int a = np2 / HWp;
      int r1 = np2 - a * HWp;
      int h = r1 / W;
      int w = r1 - h * W;
      size_t ob = ((size_t)(a * outHp + h + outPad) * outWp + (w + outPad)) * BN +
                  wc * 64 + un * 8;
      *reinterpret_cast<uint4*>(out + ob) = qv;
    }
  }
}

// ---------------------------------------------------------------------------
// box-mean pooling over y slice [2][100][352][256] bf16(permuted) -> desc fp32
__global__ void pool_k(const u16* __restrict__ y, const int* __restrict__ boxes,
                       float* __restrict__ desc) {
  int blk = blockIdx.x;  // local: a*50 + k, a in 0..1
  const int* bx = boxes + blk * 4;
  int a = blk / 50;
  int l = bx[0], r = bx[1], u = bx[2], d = bx[3];
  int c = threadIdx.x;
  float s = 0.f;
  for (int h = u; h < d; ++h) {
    const u16* row = y + ((size_t)(a * H + h) * W) * 256 + c;
    for (int w2 = l; w2 < r; ++w2) s += bf2f(row[(size_t)w2 * 256]);
  }
  desc[(size_t)blk * 256 + chlog(c)] = s / (float)((d - u) * (r - l));
}

// ---------------------------------------------------------------------------
extern "C" void kernel_launch(void* const* d_in, const int* in_sizes, int n_in,
                              void* d_out, int out_size, void* d_ws, size_t ws_size,
                              hipStream_t stream) {
  const float* feature = (const float*)d_in[0];
  const int* boxes = (const int*)d_in[1];
  const float* w1a = (const float*)d_in[2];
  const float* b1a = (const float*)d_in[3];
  const float* w1b = (const float*)d_in[4];
  const float* b1b = (const float*)d_in[5];
  const float* w2a = (const float*)d_in[6];
  const float* b2a = (const float*)d_in[7];
  const float* w2b = (const float*)d_in[8];
  const float* b2b = (const float*)d_in[9];
  const float* w3a = (const float*)d_in[10];
  const float* b3a = (const float*)d_in[11];
  const float* w3b = (const float*)d_in[12];
  const float* b3b = (const float*)d_in[13];
  const float* wDa = (const float*)d_in[14];
  const float* bDa = (const float*)d_in[15];
  const float* wDb = (const float*)d_in[16];
  const float* bDb = (const float*)d_in[17];
  const float* wF = (const float*)d_in[18];
  const float* bF = (const float*)d_in[19];

  // ---- workspace arena (slice buffers): total ~118.7 MiB
  char* ws = (char*)d_ws;
  const size_t SZ128 = (size_t)ALOC * HP * WP * 128 * 2;  // 18,487,296 B
  const size_t SZ256 = (size_t)ALOC * HP * WP * 256 * 2;  // 36,974,592 B
  const size_t SZ64  = (size_t)ALOC * HP * WP * 64 * 2;   //  9,243,648 B
  u16* X  = (u16*)(ws);
  u16* Y  = (u16*)(ws + SZ128);
  u16* S0 = (u16*)(ws + 2 * SZ128);
  u16* S1 = (u16*)(ws + 2 * SZ128 + SZ256);
  u16* in64 = (u16*)(ws + 2 * SZ128 + 2 * SZ256);
  u16* rp = (u16*)(ws + 2 * SZ128 + 2 * SZ256 + SZ64);

  const size_t o1a = 0;
  const size_t o1b = o1a + (size_t)9 * 64 * 128;
  const size_t o2a = o1b + (size_t)9 * 128 * 128;
  const size_t o2b = o2a + (size_t)9 * 128 * 128;
  const size_t o3a = o2b + (size_t)9 * 128 * 128;
  const size_t o3b = o3a + (size_t)9 * 128 * 256;
  const size_t oDa = o3b + (size_t)9 * 256 * 256;
  const size_t oDb = oDa + (size_t)9 * 256 * 256;
  const size_t oF = oDb + (size_t)256 * 256;

  auto rpk = [&](const float* wsrc, size_t off, int O, int I, int taps) {
    int total = O * I * taps;
    repack_w<<<(total + 255) / 256, 256, 0, stream>>>(wsrc, rp + off, O, I, taps);
  };
  rpk(w1a, o1a, 128, 64, 9);
  rpk(w1b, o1b, 128, 128, 9);
  rpk(w2a, o2a, 128, 128, 9);
  rpk(w2b, o2b, 128, 128, 9);
  rpk(w3a, o3a, 256, 128, 9);
  rpk(w3b, o3b, 256, 256, 9);
  rpk(wDa, oDa, 256, 256, 9);
  rpk(wDb, oDb, 256, 256, 1);
  rpk(wF, oF, 256, 256, 1);

  // borders never corrupted: zero once per call
  zero_border<64><<<(ALOC * NB * 8 + 255) / 256, 256, 0, stream>>>(in64, ALOC);
  zero_border<128><<<(ALOC * NB * 16 + 255) / 256, 256, 0, stream>>>(X, ALOC);
  zero_border<128><<<(ALOC * NB * 16 + 255) / 256, 256, 0, stream>>>(Y, ALOC);
  zero_border<256><<<(ALOC * NB * 32 + 255) / 256, 256, 0, stream>>>(S1, ALOC);

  const int G = NPIXL / 128;  // 550
  for (int a0 = 0; a0 < AG; a0 += ALOC) {
    // S0's padded border was overwritten by previous slice's unpadded convF
    zero_border<256><<<(ALOC * NB * 32 + 255) / 256, 256, 0, stream>>>(S0, ALOC);

    convert_feat<<<NPIXL * 64 / 256, 256, 0, stream>>>(
        feature + (size_t)a0 * 64 * H * W, in64);

    conv_k<64, 128, 9><<<G, 256, 0, stream>>>(in64, rp + o1a, b1a, X, HP, WP, 1);
    conv_k<128, 128, 9><<<G, 256, 0, stream>>>(X, rp + o1b, b1b, Y, HP, WP, 1);
    conv_k<128, 128, 9><<<G, 256, 0, stream>>>(Y, rp + o2a, b2a, X, HP, WP, 1);
    conv_k<128, 128, 9><<<G, 256, 0, stream>>>(X, rp + o2b, b2b, Y, HP, WP, 1);
    conv_k<128, 256, 9><<<G, 512, 0, stream>>>(Y, rp + o3a, b3a, S0, HP, WP, 1);
    conv_k<256, 256, 9><<<G, 512, 0, stream>>>(S0, rp + o3b, b3b, S1, HP, WP, 1);
    conv_k<256, 256, 9><<<G, 512, 0, stream>>>(S1, rp + oDa, bDa, S0, HP, WP, 1);
    conv_k<256, 256, 1><<<G, 512, 0, stream>>>(S0, rp + oDb, bDb, S1, HP, WP, 1);
    conv_k<256, 256, 1><<<G, 512, 0, stream>>>(S1, rp + oF, bF, S0, H, W, 0);

    pool_k<<<ALOC * 50, 256, 0, stream>>>(S0, boxes + (size_t)a0 * 50 * 4,
                                          ((float*)d_out) + (size_t)a0 * 50 * 256);
  }
}

// Round 6
// 1689.516 us; speedup vs baseline: 4.0625x; 1.2509x over previous
//
#include <hip/hip_runtime.h>
#include <hip/hip_bf16.h>

typedef unsigned int u32;
typedef unsigned short u16;
typedef __attribute__((ext_vector_type(8))) short bf16x8;   // 8 bf16 = 4 VGPRs
typedef __attribute__((ext_vector_type(4))) float f32x4;

#define DEVI __device__ __forceinline__

constexpr int AG = 8, H = 100, W = 352, HP = 102, WP = 354;
constexpr int HWp = H * W;          // 35200
constexpr int NB = 2 * WP + 2 * H;  // 908 border pixels per agent

DEVI u16 f2bf(float f) {
  __hip_bfloat16 h = __float2bfloat16(f);
  return *reinterpret_cast<u16*>(&h);
}
DEVI float bf2f(u16 v) { return __uint_as_float(((u32)v) << 16); }

// interleaved channel order within each 32-block: stored 8v+j <-> logical
// {4v+j (j<4), 16+4v+(j-4) (j>=4)} so one 16B unit = one MFMA k-fragment.
DEVI int chperm(int j) { int v = j >> 3, r = j & 7; return (r < 4) ? 4 * v + r : 16 + 4 * v + (r - 4); }
DEVI int chlog(int c) { return (c & ~31) + chperm(c & 31); }

typedef __attribute__((address_space(1))) const u32 as1c_u32;
typedef __attribute__((address_space(3))) u32 as3_u32;
DEVI void gload16(const u16* g, u16* l) {
  __builtin_amdgcn_global_load_lds((as1c_u32*)(const void*)g, (as3_u32*)(void*)l, 16, 0, 0);
}

template <int N> DEVI void waitcnt_vm() {
  if constexpr (N == 0) asm volatile("s_waitcnt vmcnt(0)" ::: "memory");
  else if constexpr (N == 3) asm volatile("s_waitcnt vmcnt(3)" ::: "memory");
  else if constexpr (N == 4) asm volatile("s_waitcnt vmcnt(4)" ::: "memory");
  else asm volatile("s_waitcnt vmcnt(0)" ::: "memory");
}

// ---------------------------------------------------------------------------
// feature slice fp32 NCHW -> padded NHWC(permuted) bf16 interior
__global__ void convert_feat(const float* __restrict__ f, u16* __restrict__ dst) {
  int idx = blockIdx.x * 256 + threadIdx.x;
  int c = idx & 63;
  int np = idx >> 6;
  int a = np / HWp;
  int r1 = np - a * HWp;
  int h = r1 / W;
  int w = r1 - h * W;
  int lc = (c & 32) + chperm(c & 31);
  dst[((size_t)(a * HP + h + 1) * WP + (w + 1)) * 64 + c] =
      f2bf(f[((size_t)(a * 64 + lc) * H + h) * W + w]);
}

// zero the 1-pixel border of a padded NHWC buffer with C channels, nA agents
template <int C>
__global__ void zero_border(u16* __restrict__ buf, int nA) {
  constexpr int CH = C / 8;
  int idx = blockIdx.x * 256 + threadIdx.x;
  int pix = idx / CH;
  int cc = (idx - pix * CH) * 8;
  if (pix >= nA * NB) return;
  int a = pix / NB;
  int b = pix - a * NB;
  int h, w;
  if (b < WP) { h = 0; w = b; }
  else if (b < 2 * WP) { h = HP - 1; w = b - WP; }
  else {
    int bb = b - 2 * WP;
    int bb2 = (bb < H) ? bb : bb - H;
    h = 1 + bb2;
    w = (bb < H) ? 0 : (WP - 1);
  }
  size_t off = ((size_t)(a * HP + h) * WP + w) * C + cc;
  *reinterpret_cast<uint4*>(buf + off) = make_uint4(0u, 0u, 0u, 0u);
}

// w [O][I][kh][kw] fp32 -> rp[s=t*KB+kb][r:O][u:8][jj:8] bf16 with the LDS
// row-XOR swizzle baked in: stored (r,u) holds logical unit lu = u^(r&7).
__global__ void repack_w(const float* __restrict__ w, u16* __restrict__ rp,
                         int O, int I, int taps) {
  int idx = blockIdx.x * 256 + threadIdx.x;
  int total = O * I * taps;
  if (idx >= total) return;
  int jj = idx & 7;
  int u = (idx >> 3) & 7;
  int r = (idx >> 6) % O;
  int s = idx / (O * 64);
  int KB = I >> 6;
  int kb = s % KB;
  int t = s / KB;
  int lu = u ^ (r & 7);
  int g = lu & 3, j32 = lu >> 2;
  int cp = (jj < 4) ? 4 * g + jj : 16 + 4 * g + (jj - 4);
  int i = kb * 64 + j32 * 32 + cp;
  int o = (r & ~31) + chperm(r & 31);
  rp[idx] = f2bf(w[((size_t)o * I + i) * taps + t]);
}

// ---------------------------------------------------------------------------
// Implicit-GEMM conv, BK=64, BN=COUT, double-buffered LDS with counted-vmcnt
// pipeline (T3+T4) and setprio around MFMA clusters (T5).
template <int CIN, int BN, int TAPS>
__global__ __launch_bounds__(BN * 2, 2) void conv_k(
    const u16* __restrict__ in, const u16* __restrict__ wrp,
    const float* __restrict__ bias, u16* __restrict__ out,
    int outHp, int outWp, int outPad) {
  constexpr int BM = 128, BK = 64;
  constexpr int KB = CIN / BK;         // 1,2,4
  constexpr int KS = TAPS * KB;
  constexpr int NT = BN * 2;           // threads
  constexpr int WN = BN / 64;          // waves along N
  constexpr int ACH = 1024 / NT;       // A chunks/thread (4 or 2)
  constexpr int AH = ACH / 2;          // A chunks per half
  constexpr int BH = 2;                // B chunks per half
  constexpr int HALF = AH + BH;        // loads per half (3 or 4)
  constexpr int ASZ = BM * BK;         // elements per A buffer
  constexpr int BSZ = BN * BK;
  __shared__ u16 smem[2 * (ASZ + BSZ)];  // dbuf: A0,A1,B0,B1

  const int tid = threadIdx.x;
  const int lane = tid & 63;
  const int wid = tid >> 6;
  const int wr = wid / WN;             // 0..1
  const int wc = wid % WN;

  // bijective XCD-aware remap (m204)
  int nwg = gridDim.x;
  int orig = blockIdx.x;
  int q = nwg >> 3, r8 = nwg & 7;
  int xcd = orig & 7, pos = orig >> 3;
  int wg = (xcd < r8 ? xcd * (q + 1) : r8 * (q + 1) + (xcd - r8) * q) + pos;
  const int n0 = wg * BM;

  // A staging addresses: chunk c = p*8+u; global supplies lu = u^(p&7)
  int aoff[ACH];
#pragma unroll
  for (int i = 0; i < ACH; ++i) {
    int c = tid + i * NT;
    int p = c >> 3, u = c & 7;
    int lu = u ^ (p & 7);
    int np2 = n0 + p;
    int a = np2 / HWp;
    int r1 = np2 - a * HWp;
    int h = r1 / W;
    int w = r1 - h * W;
    aoff[i] = ((a * HP + h + 1) * WP + (w + 1)) * CIN + lu * 8;
  }

  f32x4 acc[4][4];
#pragma unroll
  for (int m = 0; m < 4; ++m)
#pragma unroll
    for (int n = 0; n < 4; ++n) acc[m][n] = f32x4{0.f, 0.f, 0.f, 0.f};

  const int g = lane >> 4;
  const int arow = lane & 15;
  const int fk = arow & 7;

  // stage half h (0/1) of K-step s into parity s&1
  auto stage = [&](int s, int h) {
    int par = s & 1;
    u16* Ad = smem + par * ASZ;
    u16* Bd = smem + 2 * ASZ + par * BSZ;
    int t = (TAPS == 1) ? 0 : s / KB;
    int kb = (TAPS == 1) ? s : s - t * KB;
    int doff = kb * BK + ((TAPS == 9) ? ((t / 3 - 1) * WP + (t % 3 - 1)) * CIN : 0);
    const u16* wtile = wrp + (size_t)s * BSZ;
#pragma unroll
    for (int i = h * AH; i < h * AH + AH; ++i)
      gload16(in + aoff[i] + doff, Ad + (tid + i * NT) * 8);
#pragma unroll
    for (int i = h * BH; i < h * BH + BH; ++i)
      gload16(wtile + (tid + i * NT) * 8, Bd + (tid + i * NT) * 8);
  };

  stage(0, 0);
  stage(0, 1);

  for (int s = 0; s < KS; ++s) {
    int par = s & 1;
    const u16* Ab = smem + par * ASZ;
    const u16* Bb = smem + 2 * ASZ + par * BSZ;
    if (s + 1 < KS) {
      stage(s + 1, 0);                 // half0 of next tile in flight
      waitcnt_vm<HALF>();              // this tile's loads landed
    } else {
      waitcnt_vm<0>();
    }
    __builtin_amdgcn_s_barrier();      // tile s visible to all waves

#pragma unroll
    for (int j = 0; j < 2; ++j) {
      bf16x8 af[4], bfr[4];
#pragma unroll
      for (int m = 0; m < 4; ++m)
        af[m] = *reinterpret_cast<const bf16x8*>(
            Ab + (wr * 64 + m * 16 + arow) * 64 + (((j * 4 + g) ^ fk) << 3));
#pragma unroll
      for (int n = 0; n < 4; ++n)
        bfr[n] = *reinterpret_cast<const bf16x8*>(
            Bb + (wc * 64 + n * 16 + arow) * 64 + (((j * 4 + g) ^ fk) << 3));
      __builtin_amdgcn_s_setprio(1);
#pragma unroll
      for (int m = 0; m < 4; ++m)
#pragma unroll
        for (int n = 0; n < 4; ++n)
          acc[m][n] = __builtin_amdgcn_mfma_f32_16x16x32_bf16(af[m], bfr[n], acc[m][n], 0, 0, 0);
      __builtin_amdgcn_s_setprio(0);
      if (j == 0 && s + 1 < KS) stage(s + 1, 1);  // half1 under phase-1 compute
    }
    __builtin_amdgcn_s_barrier();      // all reads of parity done -> safe to overwrite
  }

  // ---- epilogue: bias+relu -> per-wave 4KB LDS tile (2 passes of 32 px)
  __syncthreads();
  float bs[4];
#pragma unroll
  for (int n = 0; n < 4; ++n) bs[n] = bias[chlog(wc * 64 + n * 16 + arow)];
  u16* et = smem + wid * 2048;  // 32 px x 64 ch per wave
#pragma unroll
  for (int pp = 0; pp < 2; ++pp) {
    if (pp) __syncthreads();
#pragma unroll
    for (int mm = 0; mm < 2; ++mm) {
      int m = pp * 2 + mm;
#pragma unroll
      for (int rg = 0; rg < 4; ++rg) {
        int row = mm * 16 + g * 4 + rg;  // 0..31; (row>>2)&3 == g
#pragma unroll
        for (int n = 0; n < 4; ++n) {
          int col = (n * 16 + arow) ^ (g << 4);
          et[row * 64 + col] = f2bf(fmaxf(acc[m][n][rg] + bs[n], 0.f));
        }
      }
    }
    __syncthreads();
#pragma unroll
    for (int jj = 0; jj < 4; ++jj) {
      int p = jj * 8 + (lane >> 3);  // 0..31
      int un = lane & 7;
      int su = un ^ (((p >> 2) & 3) << 1);
      uint4 qv = *reinterpret_cast<const uint4*>(et + p * 64 + su * 8);
      int np2 = n0 + wr * 64 + pp * 32 + p;
      int a = np2 / HWp;
      int r1 = np2 - a * HWp;
      int h = r1 / W;
      int w = r1 - h * W;
      size_t ob = ((size_t)(a * outHp + h + outPad) * outWp + (w + outPad)) * BN +
                  wc * 64 + un * 8;
      *reinterpret_cast<uint4*>(out + ob) = qv;
    }
  }
}

// ---------------------------------------------------------------------------
// box-mean pooling over y slice [nA][100][352][256] bf16(permuted) -> desc fp32
__global__ void pool_k(const u16* __restrict__ y, const int* __restrict__ boxes,
                       float* __restrict__ desc) {
  int blk = blockIdx.x;  // local: a*50 + k
  const int* bx = boxes + blk * 4;
  int a = blk / 50;
  int l = bx[0], r = bx[1], u = bx[2], d = bx[3];
  int c = threadIdx.x;
  float s = 0.f;
  for (int h = u; h < d; ++h) {
    const u16* row = y + ((size_t)(a * H + h) * W) * 256 + c;
    for (int w2 = l; w2 < r; ++w2) s += bf2f(row[(size_t)w2 * 256]);
  }
  desc[(size_t)blk * 256 + chlog(c)] = s / (float)((d - u) * (r - l));
}

// ---------------------------------------------------------------------------
extern "C" void kernel_launch(void* const* d_in, const int* in_sizes, int n_in,
                              void* d_out, int out_size, void* d_ws, size_t ws_size,
                              hipStream_t stream) {
  const float* feature = (const float*)d_in[0];
  const int* boxes = (const int*)d_in[1];
  const float* w1a = (const float*)d_in[2];
  const float* b1a = (const float*)d_in[3];
  const float* w1b = (const float*)d_in[4];
  const float* b1b = (const float*)d_in[5];
  const float* w2a = (const float*)d_in[6];
  const float* b2a = (const float*)d_in[7];
  const float* w2b = (const float*)d_in[8];
  const float* b2b = (const float*)d_in[9];
  const float* w3a = (const float*)d_in[10];
  const float* b3a = (const float*)d_in[11];
  const float* w3b = (const float*)d_in[12];
  const float* b3b = (const float*)d_in[13];
  const float* wDa = (const float*)d_in[14];
  const float* bDa = (const float*)d_in[15];
  const float* wDb = (const float*)d_in[16];
  const float* bDb = (const float*)d_in[17];
  const float* wF = (const float*)d_in[18];
  const float* bF = (const float*)d_in[19];

  const size_t WB = (size_t)2 * ((size_t)9 * 64 * 128 + 3 * 9 * 128 * 128 +
                                 (size_t)9 * 128 * 256 + 2 * 9 * 256 * 256 +
                                 2 * 256 * 256);  // repacked weight bytes
  // per-agent activation bytes: (128+128+256+256+64) ch * HP*WP * 2B
  const size_t PER_A = (size_t)832 * HP * WP * 2;
  int aloc = (ws_size >= 4 * PER_A + WB) ? 4 : 2;  // agents per slice
  const int npixl = aloc * HWp;

  char* ws = (char*)d_ws;
  const size_t SZ128 = (size_t)aloc * HP * WP * 128 * 2;
  const size_t SZ256 = (size_t)aloc * HP * WP * 256 * 2;
  const size_t SZ64  = (size_t)aloc * HP * WP * 64 * 2;
  u16* X  = (u16*)(ws);
  u16* Y  = (u16*)(ws + SZ128);
  u16* S0 = (u16*)(ws + 2 * SZ128);
  u16* S1 = (u16*)(ws + 2 * SZ128 + SZ256);
  u16* in64 = (u16*)(ws + 2 * SZ128 + 2 * SZ256);
  u16* rp = (u16*)(ws + 2 * SZ128 + 2 * SZ256 + SZ64);

  const size_t o1a = 0;
  const size_t o1b = o1a + (size_t)9 * 64 * 128;
  const size_t o2a = o1b + (size_t)9 * 128 * 128;
  const size_t o2b = o2a + (size_t)9 * 128 * 128;
  const size_t o3a = o2b + (size_t)9 * 128 * 128;
  const size_t o3b = o3a + (size_t)9 * 128 * 256;
  const size_t oDa = o3b + (size_t)9 * 256 * 256;
  const size_t oDb = oDa + (size_t)9 * 256 * 256;
  const size_t oF = oDb + (size_t)256 * 256;

  auto rpk = [&](const float* wsrc, size_t off, int O, int I, int taps) {
    int total = O * I * taps;
    repack_w<<<(total + 255) / 256, 256, 0, stream>>>(wsrc, rp + off, O, I, taps);
  };
  rpk(w1a, o1a, 128, 64, 9);
  rpk(w1b, o1b, 128, 128, 9);
  rpk(w2a, o2a, 128, 128, 9);
  rpk(w2b, o2b, 128, 128, 9);
  rpk(w3a, o3a, 256, 128, 9);
  rpk(w3b, o3b, 256, 256, 9);
  rpk(wDa, oDa, 256, 256, 9);
  rpk(wDb, oDb, 256, 256, 1);
  rpk(wF, oF, 256, 256, 1);

  // borders never corrupted: zero once per call
  zero_border<64><<<(aloc * NB * 8 + 255) / 256, 256, 0, stream>>>(in64, aloc);
  zero_border<128><<<(aloc * NB * 16 + 255) / 256, 256, 0, stream>>>(X, aloc);
  zero_border<128><<<(aloc * NB * 16 + 255) / 256, 256, 0, stream>>>(Y, aloc);
  zero_border<256><<<(aloc * NB * 32 + 255) / 256, 256, 0, stream>>>(S1, aloc);

  const int G = npixl / 128;  // 550 or 1100
  for (int a0 = 0; a0 < AG; a0 += aloc) {
    // S0's padded border was overwritten by previous slice's unpadded convF
    zero_border<256><<<(aloc * NB * 32 + 255) / 256, 256, 0, stream>>>(S0, aloc);

    convert_feat<<<npixl * 64 / 256, 256, 0, stream>>>(
        feature + (size_t)a0 * 64 * H * W, in64);

    conv_k<64, 128, 9><<<G, 256, 0, stream>>>(in64, rp + o1a, b1a, X, HP, WP, 1);
    conv_k<128, 128, 9><<<G, 256, 0, stream>>>(X, rp + o1b, b1b, Y, HP, WP, 1);
    conv_k<128, 128, 9><<<G, 256, 0, stream>>>(Y, rp + o2a, b2a, X, HP, WP, 1);
    conv_k<128, 128, 9><<<G, 256, 0, stream>>>(X, rp + o2b, b2b, Y, HP, WP, 1);
    conv_k<128, 256, 9><<<G, 512, 0, stream>>>(Y, rp + o3a, b3a, S0, HP, WP, 1);
    conv_k<256, 256, 9><<<G, 512, 0, stream>>>(S0, rp + o3b, b3b, S1, HP, WP, 1);
    conv_k<256, 256, 9><<<G, 512, 0, stream>>>(S1, rp + oDa, bDa, S0, HP, WP, 1);
    conv_k<256, 256, 1><<<G, 512, 0, stream>>>(S0, rp + oDb, bDb, S1, HP, WP, 1);
    conv_k<256, 256, 1><<<G, 512, 0, stream>>>(S1, rp + oF, bF, S0, H, W, 0);

    pool_k<<<aloc * 50, 256, 0, stream>>>(S0, boxes + (size_t)a0 * 50 * 4,
                                          ((float*)d_out) + (size_t)a0 * 50 * 256);
  }
}